// Round 2
// baseline (3048.058 us; speedup 1.0000x reference)
//
#include <hip/hip_runtime.h>
#include <hip/hip_bf16.h>

typedef __attribute__((ext_vector_type(8))) short short8;
typedef __attribute__((ext_vector_type(4))) float f32x4;

__device__ __forceinline__ float bf2f(unsigned short u) {
    union { unsigned int i; float f; } c; c.i = ((unsigned int)u) << 16; return c.f;
}
__device__ __forceinline__ unsigned short f2bf(float f) {
    __hip_bfloat16 h = __float2bfloat16(f);   // RNE
    union { __hip_bfloat16 h; unsigned short u; } c; c.h = h; return c.u;
}
__device__ __forceinline__ float gelu_exact(float x) {
    return 0.5f * x * (1.0f + erff(x * 0.7071067811865475f));
}

// C = A[N,K] @ W[128,K]^T (+ epilogue). W is bf16, bias fp32, fp32 accum.
// Block = 256 thr = 4 waves; tile 64 rows x 128 cols; wave = 16 rows.
// AF32: A is fp32 (converted to bf16 inline). OUTF32: write fp32 else bf16.
// EPI 0: out = acc + bias
// EPI 1: out = gelu(acc + deg[row]*bias)   (edge_sum path)
template<int K, int EPI, bool AF32, bool OUTF32>
__launch_bounds__(256)
__global__ void gemm_bt(const void* __restrict__ Av,
                        const unsigned short* __restrict__ W,
                        const float* __restrict__ bias,   // [128] fp32
                        void* __restrict__ outv,
                        int out_stride, int out_col_off,
                        const int* __restrict__ deg,
                        int Nrows)
{
    const int wave = threadIdx.x >> 6;
    const int lane = threadIdx.x & 63;
    const int m    = lane & 15;
    const int kq   = lane >> 4;             // k-group 0..3
    const int row  = blockIdx.x * 64 + wave * 16 + m;
    const bool rowok = row < Nrows;

    f32x4 acc[8];
#pragma unroll
    for (int i = 0; i < 8; i++) acc[i] = (f32x4){0.f, 0.f, 0.f, 0.f};

    for (int kb = 0; kb < K / 32; kb++) {
        const int k0 = kb * 32 + kq * 8;
        short8 a = (short8){0,0,0,0,0,0,0,0};
        if (rowok) {
            if (AF32) {
                const float* arow = (const float*)Av + (size_t)row * K;
                float4 f0 = *(const float4*)(arow + k0);
                float4 f1 = *(const float4*)(arow + k0 + 4);
                a[0] = (short)f2bf(f0.x); a[1] = (short)f2bf(f0.y);
                a[2] = (short)f2bf(f0.z); a[3] = (short)f2bf(f0.w);
                a[4] = (short)f2bf(f1.x); a[5] = (short)f2bf(f1.y);
                a[6] = (short)f2bf(f1.z); a[7] = (short)f2bf(f1.w);
            } else {
                const unsigned short* arow = (const unsigned short*)Av + (size_t)row * K;
                a = *(const short8*)(arow + k0);
            }
        }
#pragma unroll
        for (int nt = 0; nt < 8; nt++) {
            const int j = nt * 16 + m;      // output col / W row
            short8 b = *(const short8*)(W + (size_t)j * K + k0);
            acc[nt] = __builtin_amdgcn_mfma_f32_16x16x32_bf16(a, b, acc[nt], 0, 0, 0);
        }
    }

    // C/D layout (verified m89/m91): col = lane&15, row = (lane>>4)*4 + reg
    const int ocol = lane & 15;
    const int orow_base = blockIdx.x * 64 + wave * 16 + (lane >> 4) * 4;
#pragma unroll
    for (int nt = 0; nt < 8; nt++) {
        const int col = nt * 16 + ocol;
        const float bval = bias[col];
#pragma unroll
        for (int r = 0; r < 4; r++) {
            const int orow = orow_base + r;
            if (orow < Nrows) {
                float v;
                if (EPI == 1) {
                    const float dg = (float)deg[orow];
                    v = gelu_exact(acc[nt][r] + dg * bval);
                } else {
                    v = acc[nt][r] + bval;
                }
                const size_t oi = (size_t)orow * out_stride + out_col_off + col;
                if (OUTF32) ((float*)outv)[oi] = v;
                else        ((unsigned short*)outv)[oi] = f2bf(v);
            }
        }
    }
}

// fp32 -> bf16 for the three weight matrices in one launch
__global__ void cvt3_kernel(const float* __restrict__ s0, int n0,
                            const float* __restrict__ s1, int n1,
                            const float* __restrict__ s2, int n2,
                            unsigned short* __restrict__ d0,
                            unsigned short* __restrict__ d1,
                            unsigned short* __restrict__ d2) {
    int t4 = (blockIdx.x * blockDim.x + threadIdx.x) * 4;
    if (t4 < n0) {
        float4 f = *(const float4*)(s0 + t4);
        ushort4 o = { f2bf(f.x), f2bf(f.y), f2bf(f.z), f2bf(f.w) };
        *(ushort4*)(d0 + t4) = o;
    }
    if (t4 < n1) {
        float4 f = *(const float4*)(s1 + t4);
        ushort4 o = { f2bf(f.x), f2bf(f.y), f2bf(f.z), f2bf(f.w) };
        *(ushort4*)(d1 + t4) = o;
    }
    if (t4 < n2) {
        float4 f = *(const float4*)(s2 + t4);
        ushort4 o = { f2bf(f.x), f2bf(f.y), f2bf(f.z), f2bf(f.w) };
        *(ushort4*)(d2 + t4) = o;
    }
}

// Detect whether edge_index buffer is int64 (little-endian: odd int32 words
// of the src row are all-zero high halves) or already int32.
__global__ void detect_kernel(const int* __restrict__ ei, int E, int* __restrict__ flag) {
    if (threadIdx.x == 0 && blockIdx.x == 0) {
        int orv = 0;
        int lim = (E < 64) ? E : 64;
        for (int i = 0; i < lim; i++) orv |= ei[2 * i + 1];
        flag[0] = (orv == 0) ? 1 : 0;
    }
}

__device__ __forceinline__ int ld_src(const int* ei, const int* flag, int E, int e) {
    return flag[0] ? ei[2 * (size_t)e] : ei[e];
}
__device__ __forceinline__ int ld_dst(const int* ei, const int* flag, int E, int e) {
    return flag[0] ? ei[2 * (size_t)(E + e)] : ei[E + e];
}

__global__ void deg_kernel(const int* __restrict__ ei, const int* __restrict__ flag,
                           int* __restrict__ deg, int E, int Nn) {
    int e = blockIdx.x * blockDim.x + threadIdx.x;
    if (e >= E) return;
    int s = ld_src(ei, flag, E, e);
    if ((unsigned)s >= (unsigned)Nn) return;   // defensive
    atomicAdd(&deg[s], 1);
}

// nbr_sum[src[e]] += node[dst[e]]  -- 16 threads/edge, 8 channels each, fp32 atomics
__global__ void scatter_kernel(const int* __restrict__ ei, const int* __restrict__ flag,
                               const unsigned short* __restrict__ node,
                               float* __restrict__ nbr, int E, int Nn) {
    int t = blockIdx.x * blockDim.x + threadIdx.x;
    int e = t >> 4;
    if (e >= E) return;
    int c = (t & 15) * 8;
    int s = ld_src(ei, flag, E, e);
    int d = ld_dst(ei, flag, E, e);
    if ((unsigned)s >= (unsigned)Nn || (unsigned)d >= (unsigned)Nn) return;  // defensive
    short8 v = *(const short8*)(node + (size_t)d * 128 + c);
    float* op = nbr + (size_t)s * 128 + c;
#pragma unroll
    for (int j = 0; j < 8; j++)
        atomicAdd(op + j, bf2f((unsigned short)v[j]));
}

// Build A2 = [deg*node | nbr] (bf16, [N,256]) and Apre[:,0:256] = gelu([node|nbr])
__global__ void build_kernel(const unsigned short* __restrict__ node,
                             const float* __restrict__ nbr,
                             const int* __restrict__ deg,
                             unsigned short* __restrict__ A2,
                             unsigned short* __restrict__ Apre, int N) {
    int t = blockIdx.x * blockDim.x + threadIdx.x;
    int v = t >> 5;
    if (v >= N) return;
    int k = (t & 31) * 4;
    float dg = (float)deg[v];
    ushort4 nd = *(const ushort4*)(node + (size_t)v * 128 + k);
    float4  nb = *(const float4*)(nbr + (size_t)v * 128 + k);
    float nf[4] = { bf2f(nd.x), bf2f(nd.y), bf2f(nd.z), bf2f(nd.w) };
    float bf[4] = { nb.x, nb.y, nb.z, nb.w };
    ushort4 o;
    // A2[:,0:128] = deg*node
    o.x = f2bf(dg * nf[0]); o.y = f2bf(dg * nf[1]); o.z = f2bf(dg * nf[2]); o.w = f2bf(dg * nf[3]);
    *(ushort4*)(A2 + (size_t)v * 256 + k) = o;
    // A2[:,128:256] = nbr
    o.x = f2bf(bf[0]); o.y = f2bf(bf[1]); o.z = f2bf(bf[2]); o.w = f2bf(bf[3]);
    *(ushort4*)(A2 + (size_t)v * 256 + 128 + k) = o;
    // Apre[:,0:128] = gelu(node)
    o.x = f2bf(gelu_exact(nf[0])); o.y = f2bf(gelu_exact(nf[1]));
    o.z = f2bf(gelu_exact(nf[2])); o.w = f2bf(gelu_exact(nf[3]));
    *(ushort4*)(Apre + (size_t)v * 384 + k) = o;
    // Apre[:,128:256] = gelu(nbr)
    o.x = f2bf(gelu_exact(bf[0])); o.y = f2bf(gelu_exact(bf[1]));
    o.z = f2bf(gelu_exact(bf[2])); o.w = f2bf(gelu_exact(bf[3]));
    *(ushort4*)(Apre + (size_t)v * 384 + 128 + k) = o;
}

extern "C" void kernel_launch(void* const* d_in, const int* in_sizes, int n_in,
                              void* d_out, int out_size, void* d_ws, size_t ws_size,
                              hipStream_t stream) {
    const float* x  = (const float*)d_in[0];
    const int*   ei = (const int*)d_in[1];
    const float* Wn = (const float*)d_in[2];
    const float* bn = (const float*)d_in[3];
    const float* We = (const float*)d_in[4];
    const float* be = (const float*)d_in[5];
    const float* Wu = (const float*)d_in[6];
    const float* bu = (const float*)d_in[7];

    const int N = in_sizes[0] / 128;
    const int E = in_sizes[1] / 2;
    const int nWn = in_sizes[2], nWe = in_sizes[4], nWu = in_sizes[6];

    char* ws = (char*)d_ws;
    size_t off = 0;
    unsigned short* node = (unsigned short*)(ws + off); off += (size_t)N * 128 * 2;
    float* nbr = (float*)(ws + off);                    off += (size_t)N * 128 * 4;
    int* deg = (int*)(ws + off);                        off += (size_t)N * 4;
    int* flag = (int*)(ws + off);                       off += 256;  // + pad
    off = (off + 255) & ~(size_t)255;
    unsigned short* A2 = (unsigned short*)(ws + off);   off += (size_t)N * 256 * 2;
    off = (off + 255) & ~(size_t)255;
    unsigned short* Apre = (unsigned short*)(ws + off); off += (size_t)N * 384 * 2;
    off = (off + 255) & ~(size_t)255;
    unsigned short* Wnb = (unsigned short*)(ws + off);  off += (size_t)nWn * 2;
    unsigned short* Web = (unsigned short*)(ws + off);  off += (size_t)nWe * 2;
    unsigned short* Wub = (unsigned short*)(ws + off);  off += (size_t)nWu * 2;

    // zero nbr (f32) + deg (contiguous)
    hipMemsetAsync(nbr, 0, (size_t)N * 128 * 4 + (size_t)N * 4, stream);

    const int mblocks = (N + 63) / 64;

    // 0a. weights fp32 -> bf16
    int maxn = nWu > nWe ? nWu : nWe; if (nWn > maxn) maxn = nWn;
    cvt3_kernel<<<(maxn / 4 + 255) / 256, 256, 0, stream>>>(Wn, nWn, We, nWe, Wu, nWu, Wnb, Web, Wub);
    // 0b. edge_index layout detect
    detect_kernel<<<1, 64, 0, stream>>>(ei, E, flag);
    // 1. node = x @ Wn^T + bn   (x fp32 -> bf16 inline)
    gemm_bt<128, 0, true, false><<<mblocks, 256, 0, stream>>>(x, Wnb, bn, node, 128, 0, nullptr, N);
    // 2a. deg histogram
    deg_kernel<<<(E + 255) / 256, 256, 0, stream>>>(ei, flag, deg, E, N);
    // 2b. nbr_sum scatter
    scatter_kernel<<<((size_t)E * 16 + 255) / 256, 256, 0, stream>>>(ei, flag, node, nbr, E, N);
    // 3. build A2 = [deg*node | nbr], Apre[:,0:256] = gelu([node|nbr])
    build_kernel<<<((size_t)N * 32 + 255) / 256, 256, 0, stream>>>(node, nbr, deg, A2, Apre, N);
    // 4. edge_sum = A2 @ We^T + deg*be, gelu -> Apre[:,256:384]
    gemm_bt<256, 1, false, false><<<mblocks, 256, 0, stream>>>(A2, Web, be, Apre, 384, 256, deg, N);
    // 5. out = Apre @ Wu^T + bu  (fp32 out)
    gemm_bt<384, 0, false, true><<<mblocks, 256, 0, stream>>>(Apre, Wub, bu, d_out, 128, 0, nullptr, N);
}

// Round 3
// 468.600 us; speedup vs baseline: 6.5046x; 6.5046x over previous
//
#include <hip/hip_runtime.h>
#include <hip/hip_bf16.h>

typedef __attribute__((ext_vector_type(8))) short short8;
typedef __attribute__((ext_vector_type(4))) float f32x4;

__device__ __forceinline__ float bf2f(unsigned short u) {
    union { unsigned int i; float f; } c; c.i = ((unsigned int)u) << 16; return c.f;
}
__device__ __forceinline__ unsigned short f2bf(float f) {
    __hip_bfloat16 h = __float2bfloat16(f);   // RNE
    union { __hip_bfloat16 h; unsigned short u; } c; c.h = h; return c.u;
}
__device__ __forceinline__ float gelu_exact(float x) {
    return 0.5f * x * (1.0f + erff(x * 0.7071067811865475f));
}

// C = A[N,K] @ W[128,K]^T (+ epilogue). W is bf16, bias fp32, fp32 accum.
// Block = 256 thr = 4 waves; tile 64 rows x 128 cols; wave = 16 rows.
// AF32: A is fp32 (converted to bf16 inline). OUTF32: write fp32 else bf16.
// EPI 0: out = acc + bias
// EPI 1: out = gelu(acc + deg[row]*bias)   (edge_sum path)
template<int K, int EPI, bool AF32, bool OUTF32>
__launch_bounds__(256)
__global__ void gemm_bt(const void* __restrict__ Av,
                        const unsigned short* __restrict__ W,
                        const float* __restrict__ bias,   // [128] fp32
                        void* __restrict__ outv,
                        int out_stride, int out_col_off,
                        const int* __restrict__ deg,
                        int Nrows)
{
    const int wave = threadIdx.x >> 6;
    const int lane = threadIdx.x & 63;
    const int m    = lane & 15;
    const int kq   = lane >> 4;             // k-group 0..3
    const int row  = blockIdx.x * 64 + wave * 16 + m;
    const bool rowok = row < Nrows;

    f32x4 acc[8];
#pragma unroll
    for (int i = 0; i < 8; i++) acc[i] = (f32x4){0.f, 0.f, 0.f, 0.f};

    for (int kb = 0; kb < K / 32; kb++) {
        const int k0 = kb * 32 + kq * 8;
        short8 a = (short8){0,0,0,0,0,0,0,0};
        if (rowok) {
            if (AF32) {
                const float* arow = (const float*)Av + (size_t)row * K;
                float4 f0 = *(const float4*)(arow + k0);
                float4 f1 = *(const float4*)(arow + k0 + 4);
                a[0] = (short)f2bf(f0.x); a[1] = (short)f2bf(f0.y);
                a[2] = (short)f2bf(f0.z); a[3] = (short)f2bf(f0.w);
                a[4] = (short)f2bf(f1.x); a[5] = (short)f2bf(f1.y);
                a[6] = (short)f2bf(f1.z); a[7] = (short)f2bf(f1.w);
            } else {
                const unsigned short* arow = (const unsigned short*)Av + (size_t)row * K;
                a = *(const short8*)(arow + k0);
            }
        }
#pragma unroll
        for (int nt = 0; nt < 8; nt++) {
            const int j = nt * 16 + m;      // output col / W row
            short8 b = *(const short8*)(W + (size_t)j * K + k0);
            acc[nt] = __builtin_amdgcn_mfma_f32_16x16x32_bf16(a, b, acc[nt], 0, 0, 0);
        }
    }

    // C/D layout (verified m89/m91): col = lane&15, row = (lane>>4)*4 + reg
    const int ocol = lane & 15;
    const int orow_base = blockIdx.x * 64 + wave * 16 + (lane >> 4) * 4;
#pragma unroll
    for (int nt = 0; nt < 8; nt++) {
        const int col = nt * 16 + ocol;
        const float bval = bias[col];
#pragma unroll
        for (int r = 0; r < 4; r++) {
            const int orow = orow_base + r;
            if (orow < Nrows) {
                float v;
                if (EPI == 1) {
                    const float dg = (float)deg[orow];
                    v = gelu_exact(acc[nt][r] + dg * bval);
                } else {
                    v = acc[nt][r] + bval;
                }
                const size_t oi = (size_t)orow * out_stride + out_col_off + col;
                if (OUTF32) ((float*)outv)[oi] = v;
                else        ((unsigned short*)outv)[oi] = f2bf(v);
            }
        }
    }
}

// fp32 -> bf16 for the three weight matrices in one launch
__global__ void cvt3_kernel(const float* __restrict__ s0, int n0,
                            const float* __restrict__ s1, int n1,
                            const float* __restrict__ s2, int n2,
                            unsigned short* __restrict__ d0,
                            unsigned short* __restrict__ d1,
                            unsigned short* __restrict__ d2) {
    int t4 = (blockIdx.x * blockDim.x + threadIdx.x) * 4;
    if (t4 < n0) {
        float4 f = *(const float4*)(s0 + t4);
        ushort4 o = { f2bf(f.x), f2bf(f.y), f2bf(f.z), f2bf(f.w) };
        *(ushort4*)(d0 + t4) = o;
    }
    if (t4 < n1) {
        float4 f = *(const float4*)(s1 + t4);
        ushort4 o = { f2bf(f.x), f2bf(f.y), f2bf(f.z), f2bf(f.w) };
        *(ushort4*)(d1 + t4) = o;
    }
    if (t4 < n2) {
        float4 f = *(const float4*)(s2 + t4);
        ushort4 o = { f2bf(f.x), f2bf(f.y), f2bf(f.z), f2bf(f.w) };
        *(ushort4*)(d2 + t4) = o;
    }
}

// Detect whether edge_index buffer is int64 (little-endian: odd int32 words
// of the src row are all-zero high halves) or already int32.
__global__ void detect_kernel(const int* __restrict__ ei, int E, int* __restrict__ flag) {
    if (threadIdx.x == 0 && blockIdx.x == 0) {
        int orv = 0;
        int lim = (E < 64) ? E : 64;
        for (int i = 0; i < lim; i++) orv |= ei[2 * i + 1];
        flag[0] = (orv == 0) ? 1 : 0;
    }
}

__device__ __forceinline__ int ld_src(const int* ei, const int* flag, int E, int e) {
    return flag[0] ? ei[2 * (size_t)e] : ei[e];
}
__device__ __forceinline__ int ld_dst(const int* ei, const int* flag, int E, int e) {
    return flag[0] ? ei[2 * (size_t)(E + e)] : ei[E + e];
}

__global__ void deg_kernel(const int* __restrict__ ei, const int* __restrict__ flag,
                           int* __restrict__ deg, int E, int Nn) {
    int e = blockIdx.x * blockDim.x + threadIdx.x;
    if (e >= E) return;
    int s = ld_src(ei, flag, E, e);
    if ((unsigned)s >= (unsigned)Nn) return;   // defensive
    atomicAdd(&deg[s], 1);
}

// Single-block exclusive scan of deg[N] -> rowptr[N+1] and cursor[N].
// 256 threads, each owns a contiguous chunk; serial scan of 256 partials.
__global__ void scan_kernel(const int* __restrict__ deg,
                            int* __restrict__ rowptr, int* __restrict__ cursor, int N) {
    __shared__ int part[257];
    const int t = threadIdx.x;
    const int chunk = (N + 255) / 256;
    const int start = t * chunk;
    const int end   = (start + chunk < N) ? start + chunk : N;
    int s = 0;
    for (int i = start; i < end; i++) s += deg[i];
    part[t] = s;
    __syncthreads();
    if (t == 0) {
        int run = 0;
        for (int i = 0; i < 256; i++) { int v = part[i]; part[i] = run; run += v; }
        part[256] = run;
        rowptr[N] = run;
    }
    __syncthreads();
    int base = part[t];
    for (int i = start; i < end; i++) {
        rowptr[i] = base;
        cursor[i] = base;
        base += deg[i];
    }
}

// CSR fill: one int atomic per edge
__global__ void fill_kernel(const int* __restrict__ ei, const int* __restrict__ flag,
                            int* __restrict__ cursor, int* __restrict__ csr, int E, int Nn) {
    int e = blockIdx.x * blockDim.x + threadIdx.x;
    if (e >= E) return;
    int s = ld_src(ei, flag, E, e);
    int d = ld_dst(ei, flag, E, e);
    if ((unsigned)s >= (unsigned)Nn || (unsigned)d >= (unsigned)Nn) return;  // defensive
    int p = atomicAdd(&cursor[s], 1);
    csr[p] = d;
}

// Gather + build fused: per node v (16 lanes, 8 ch/lane):
//   nbr = sum_{j} node[csr[j]]  (fp32 regs, no atomics)
//   A2[v]   = [deg*node[v] | nbr]          (bf16, K=256 GEMM input)
//   Apre[v][0:256] = [gelu(node[v]) | gelu(nbr)]
__global__ void gather_build_kernel(const int* __restrict__ rowptr,
                                    const int* __restrict__ csr,
                                    const unsigned short* __restrict__ node,
                                    unsigned short* __restrict__ A2,
                                    unsigned short* __restrict__ Apre, int N) {
    int t = blockIdx.x * blockDim.x + threadIdx.x;
    int v = t >> 4;
    if (v >= N) return;
    const int c = (t & 15) * 8;
    const int r0 = rowptr[v], r1 = rowptr[v + 1];
    float acc[8] = {0.f,0.f,0.f,0.f,0.f,0.f,0.f,0.f};
    for (int j = r0; j < r1; j++) {
        const int d = csr[j];
        short8 nv = *(const short8*)(node + (size_t)d * 128 + c);
#pragma unroll
        for (int k = 0; k < 8; k++) acc[k] += bf2f((unsigned short)nv[k]);
    }
    const float dg = (float)(r1 - r0);
    short8 me = *(const short8*)(node + (size_t)v * 128 + c);
    short8 o;
#pragma unroll
    for (int k = 0; k < 8; k++) o[k] = (short)f2bf(dg * bf2f((unsigned short)me[k]));
    *(short8*)(A2 + (size_t)v * 256 + c) = o;
#pragma unroll
    for (int k = 0; k < 8; k++) o[k] = (short)f2bf(acc[k]);
    *(short8*)(A2 + (size_t)v * 256 + 128 + c) = o;
#pragma unroll
    for (int k = 0; k < 8; k++) o[k] = (short)f2bf(gelu_exact(bf2f((unsigned short)me[k])));
    *(short8*)(Apre + (size_t)v * 384 + c) = o;
#pragma unroll
    for (int k = 0; k < 8; k++) o[k] = (short)f2bf(gelu_exact(acc[k]));
    *(short8*)(Apre + (size_t)v * 384 + 128 + c) = o;
}

extern "C" void kernel_launch(void* const* d_in, const int* in_sizes, int n_in,
                              void* d_out, int out_size, void* d_ws, size_t ws_size,
                              hipStream_t stream) {
    const float* x  = (const float*)d_in[0];
    const int*   ei = (const int*)d_in[1];
    const float* Wn = (const float*)d_in[2];
    const float* bn = (const float*)d_in[3];
    const float* We = (const float*)d_in[4];
    const float* be = (const float*)d_in[5];
    const float* Wu = (const float*)d_in[6];
    const float* bu = (const float*)d_in[7];

    const int N = in_sizes[0] / 128;
    const int E = in_sizes[1] / 2;
    const int nWn = in_sizes[2], nWe = in_sizes[4], nWu = in_sizes[6];

    char* ws = (char*)d_ws;
    size_t off = 0;
    unsigned short* node = (unsigned short*)(ws + off); off += (size_t)N * 128 * 2;
    int* deg = (int*)(ws + off);                        off += (size_t)N * 4;
    int* flag = (int*)(ws + off);                       off += 256;
    off = (off + 255) & ~(size_t)255;
    int* rowptr = (int*)(ws + off);                     off += (size_t)(N + 1) * 4;
    off = (off + 255) & ~(size_t)255;
    int* cursor = (int*)(ws + off);                     off += (size_t)N * 4;
    off = (off + 255) & ~(size_t)255;
    int* csr = (int*)(ws + off);                        off += (size_t)E * 4;
    off = (off + 255) & ~(size_t)255;
    unsigned short* A2 = (unsigned short*)(ws + off);   off += (size_t)N * 256 * 2;
    off = (off + 255) & ~(size_t)255;
    unsigned short* Apre = (unsigned short*)(ws + off); off += (size_t)N * 384 * 2;
    off = (off + 255) & ~(size_t)255;
    unsigned short* Wnb = (unsigned short*)(ws + off);  off += (size_t)nWn * 2;
    unsigned short* Web = (unsigned short*)(ws + off);  off += (size_t)nWe * 2;
    unsigned short* Wub = (unsigned short*)(ws + off);  off += (size_t)nWu * 2;

    // zero deg only (rowptr/cursor are fully written by scan_kernel)
    hipMemsetAsync(deg, 0, (size_t)N * 4, stream);

    const int mblocks = (N + 63) / 64;

    // 0a. weights fp32 -> bf16
    int maxn = nWu > nWe ? nWu : nWe; if (nWn > maxn) maxn = nWn;
    cvt3_kernel<<<(maxn / 4 + 255) / 256, 256, 0, stream>>>(Wn, nWn, We, nWe, Wu, nWu, Wnb, Web, Wub);
    // 0b. edge_index layout detect
    detect_kernel<<<1, 64, 0, stream>>>(ei, E, flag);
    // 1. node = x @ Wn^T + bn   (x fp32 -> bf16 inline)
    gemm_bt<128, 0, true, false><<<mblocks, 256, 0, stream>>>(x, Wnb, bn, node, 128, 0, nullptr, N);
    // 2. CSR build: histogram -> scan -> fill
    deg_kernel<<<(E + 255) / 256, 256, 0, stream>>>(ei, flag, deg, E, N);
    scan_kernel<<<1, 256, 0, stream>>>(deg, rowptr, cursor, N);
    fill_kernel<<<(E + 255) / 256, 256, 0, stream>>>(ei, flag, cursor, csr, E, N);
    // 3. gather nbr_sum + build A2 / Apre[:,0:256]  (no atomics)
    gather_build_kernel<<<((size_t)N * 16 + 255) / 256, 256, 0, stream>>>(rowptr, csr, node, A2, Apre, N);
    // 4. edge_sum = A2 @ We^T + deg*be, gelu -> Apre[:,256:384]
    gemm_bt<256, 1, false, false><<<mblocks, 256, 0, stream>>>(A2, Web, be, Apre, 384, 256, deg, N);
    // 5. out = Apre @ Wu^T + bu  (fp32 out)
    gemm_bt<384, 0, false, true><<<mblocks, 256, 0, stream>>>(Apre, Wub, bu, d_out, 128, 0, nullptr, N);
}

// Round 4
// 357.859 us; speedup vs baseline: 8.5175x; 1.3095x over previous
//
#include <hip/hip_runtime.h>
#include <hip/hip_bf16.h>

typedef __attribute__((ext_vector_type(8))) short short8;
typedef __attribute__((ext_vector_type(4))) float f32x4;

__device__ __forceinline__ float bf2f(unsigned short u) {
    union { unsigned int i; float f; } c; c.i = ((unsigned int)u) << 16; return c.f;
}
__device__ __forceinline__ unsigned short f2bf(float f) {
    __hip_bfloat16 h = __float2bfloat16(f);   // RNE
    union { __hip_bfloat16 h; unsigned short u; } c; c.h = h; return c.u;
}
__device__ __forceinline__ float gelu_exact(float x) {
    return 0.5f * x * (1.0f + erff(x * 0.7071067811865475f));
}

// C = A[N,K] @ W[128,K]^T (+ epilogue). W is bf16, bias fp32, fp32 accum.
// Block = 256 thr = 4 waves; tile 64 rows x 128 cols; wave = 16 rows.
// AF32: A is fp32 (converted to bf16 inline). OUTF32: write fp32 else bf16.
// EPI 0: out = acc + bias
// EPI 1: out = gelu(acc + deg[row]*bias)   (edge_sum path)
template<int K, int EPI, bool AF32, bool OUTF32>
__launch_bounds__(256)
__global__ void gemm_bt(const void* __restrict__ Av,
                        const unsigned short* __restrict__ W,
                        const float* __restrict__ bias,   // [128] fp32
                        void* __restrict__ outv,
                        int out_stride, int out_col_off,
                        const int* __restrict__ deg,
                        int Nrows)
{
    const int wave = threadIdx.x >> 6;
    const int lane = threadIdx.x & 63;
    const int m    = lane & 15;
    const int kq   = lane >> 4;             // k-group 0..3
    const int row  = blockIdx.x * 64 + wave * 16 + m;
    const bool rowok = row < Nrows;

    f32x4 acc[8];
#pragma unroll
    for (int i = 0; i < 8; i++) acc[i] = (f32x4){0.f, 0.f, 0.f, 0.f};

    for (int kb = 0; kb < K / 32; kb++) {
        const int k0 = kb * 32 + kq * 8;
        short8 a = (short8){0,0,0,0,0,0,0,0};
        if (rowok) {
            if (AF32) {
                const float* arow = (const float*)Av + (size_t)row * K;
                float4 f0 = *(const float4*)(arow + k0);
                float4 f1 = *(const float4*)(arow + k0 + 4);
                a[0] = (short)f2bf(f0.x); a[1] = (short)f2bf(f0.y);
                a[2] = (short)f2bf(f0.z); a[3] = (short)f2bf(f0.w);
                a[4] = (short)f2bf(f1.x); a[5] = (short)f2bf(f1.y);
                a[6] = (short)f2bf(f1.z); a[7] = (short)f2bf(f1.w);
            } else {
                const unsigned short* arow = (const unsigned short*)Av + (size_t)row * K;
                a = *(const short8*)(arow + k0);
            }
        }
#pragma unroll
        for (int nt = 0; nt < 8; nt++) {
            const int j = nt * 16 + m;      // output col / W row
            short8 b = *(const short8*)(W + (size_t)j * K + k0);
            acc[nt] = __builtin_amdgcn_mfma_f32_16x16x32_bf16(a, b, acc[nt], 0, 0, 0);
        }
    }

    // C/D layout (verified m89/m91): col = lane&15, row = (lane>>4)*4 + reg
    const int ocol = lane & 15;
    const int orow_base = blockIdx.x * 64 + wave * 16 + (lane >> 4) * 4;
#pragma unroll
    for (int nt = 0; nt < 8; nt++) {
        const int col = nt * 16 + ocol;
        const float bval = bias[col];
#pragma unroll
        for (int r = 0; r < 4; r++) {
            const int orow = orow_base + r;
            if (orow < Nrows) {
                float v;
                if (EPI == 1) {
                    const float dg = (float)deg[orow];
                    v = gelu_exact(acc[nt][r] + dg * bval);
                } else {
                    v = acc[nt][r] + bval;
                }
                const size_t oi = (size_t)orow * out_stride + out_col_off + col;
                if (OUTF32) ((float*)outv)[oi] = v;
                else        ((unsigned short*)outv)[oi] = f2bf(v);
            }
        }
    }
}

// fp32 -> bf16 for the three weight matrices in one launch
__global__ void cvt3_kernel(const float* __restrict__ s0, int n0,
                            const float* __restrict__ s1, int n1,
                            const float* __restrict__ s2, int n2,
                            unsigned short* __restrict__ d0,
                            unsigned short* __restrict__ d1,
                            unsigned short* __restrict__ d2) {
    int t4 = (blockIdx.x * blockDim.x + threadIdx.x) * 4;
    if (t4 < n0) {
        float4 f = *(const float4*)(s0 + t4);
        ushort4 o = { f2bf(f.x), f2bf(f.y), f2bf(f.z), f2bf(f.w) };
        *(ushort4*)(d0 + t4) = o;
    }
    if (t4 < n1) {
        float4 f = *(const float4*)(s1 + t4);
        ushort4 o = { f2bf(f.x), f2bf(f.y), f2bf(f.z), f2bf(f.w) };
        *(ushort4*)(d1 + t4) = o;
    }
    if (t4 < n2) {
        float4 f = *(const float4*)(s2 + t4);
        ushort4 o = { f2bf(f.x), f2bf(f.y), f2bf(f.z), f2bf(f.w) };
        *(ushort4*)(d2 + t4) = o;
    }
}

// Detect whether edge_index buffer is int64 (little-endian: odd int32 words
// of the src row are all-zero high halves) or already int32.
__global__ void detect_kernel(const int* __restrict__ ei, int E, int* __restrict__ flag) {
    if (threadIdx.x == 0 && blockIdx.x == 0) {
        int orv = 0;
        int lim = (E < 64) ? E : 64;
        for (int i = 0; i < lim; i++) orv |= ei[2 * i + 1];
        flag[0] = (orv == 0) ? 1 : 0;
    }
}

__device__ __forceinline__ int ld_src(const int* ei, const int* flag, int E, int e) {
    return flag[0] ? ei[2 * (size_t)e] : ei[e];
}
__device__ __forceinline__ int ld_dst(const int* ei, const int* flag, int E, int e) {
    return flag[0] ? ei[2 * (size_t)(E + e)] : ei[E + e];
}

__global__ void deg_kernel(const int* __restrict__ ei, const int* __restrict__ flag,
                           int* __restrict__ deg, int E, int Nn) {
    int e = blockIdx.x * blockDim.x + threadIdx.x;
    if (e >= E) return;
    int s = ld_src(ei, flag, E, e);
    if ((unsigned)s >= (unsigned)Nn) return;   // defensive
    atomicAdd(&deg[s], 1);
}

// ---- Three-phase grid-wide exclusive scan of deg[N] -> rowptr[N+1], cursor[N] ----
// Phase 1: per-block (2048 elems) reduce -> blocksum[b]
#define SCAN_ELEMS 2048   // 256 thr x 8 elems
__launch_bounds__(256)
__global__ void scan_partial(const int* __restrict__ deg, int* __restrict__ blocksum, int N) {
    __shared__ int red[256];
    const int t = threadIdx.x;
    const int base = blockIdx.x * SCAN_ELEMS + t * 8;
    int s = 0;
#pragma unroll
    for (int i = 0; i < 8; i++) {
        int idx = base + i;
        if (idx < N) s += deg[idx];
    }
    red[t] = s;
    __syncthreads();
    for (int d = 128; d > 0; d >>= 1) {
        if (t < d) red[t] += red[t + d];
        __syncthreads();
    }
    if (t == 0) blocksum[blockIdx.x] = red[0];
}

// Phase 2: serial scan of nb block sums (nb ~ 25) -> exclusive offsets; total -> rowptr[N]
__global__ void scan_offsets(int* __restrict__ blocksum, int nb,
                             int* __restrict__ rowptr, int N) {
    if (threadIdx.x == 0 && blockIdx.x == 0) {
        int run = 0;
        for (int i = 0; i < nb; i++) { int v = blocksum[i]; blocksum[i] = run; run += v; }
        rowptr[N] = run;
    }
}

// Phase 3: per-block re-scan with offset, write rowptr + cursor
__launch_bounds__(256)
__global__ void scan_apply(const int* __restrict__ deg, const int* __restrict__ blocksum,
                           int* __restrict__ rowptr, int* __restrict__ cursor, int N) {
    __shared__ int part[256];
    const int t = threadIdx.x;
    const int base = blockIdx.x * SCAN_ELEMS + t * 8;
    int d8[8];
    int s = 0;
#pragma unroll
    for (int i = 0; i < 8; i++) {
        int idx = base + i;
        d8[i] = (idx < N) ? deg[idx] : 0;
        s += d8[i];
    }
    const int mysum = s;
    part[t] = s;
    __syncthreads();
    // Hillis-Steele inclusive scan over 256 thread sums
    for (int d = 1; d < 256; d <<= 1) {
        int v = (t >= d) ? part[t - d] : 0;
        __syncthreads();
        part[t] += v;
        __syncthreads();
    }
    int run = blocksum[blockIdx.x] + part[t] - mysum;   // exclusive prefix for this thread
#pragma unroll
    for (int i = 0; i < 8; i++) {
        int idx = base + i;
        if (idx < N) {
            rowptr[idx] = run;
            cursor[idx] = run;
            run += d8[i];
        }
    }
}

// CSR fill: one int atomic per edge
__global__ void fill_kernel(const int* __restrict__ ei, const int* __restrict__ flag,
                            int* __restrict__ cursor, int* __restrict__ csr, int E, int Nn) {
    int e = blockIdx.x * blockDim.x + threadIdx.x;
    if (e >= E) return;
    int s = ld_src(ei, flag, E, e);
    int d = ld_dst(ei, flag, E, e);
    if ((unsigned)s >= (unsigned)Nn || (unsigned)d >= (unsigned)Nn) return;  // defensive
    int p = atomicAdd(&cursor[s], 1);
    csr[p] = d;
}

// Gather + build fused: per node v (16 lanes, 8 ch/lane):
//   nbr = sum_{j} node[csr[j]]  (fp32 regs, no atomics)
//   A2[v]   = [deg*node[v] | nbr]          (bf16, K=256 GEMM input)
//   Apre[v][0:256] = [gelu(node[v]) | gelu(nbr)]
__global__ void gather_build_kernel(const int* __restrict__ rowptr,
                                    const int* __restrict__ csr,
                                    const unsigned short* __restrict__ node,
                                    unsigned short* __restrict__ A2,
                                    unsigned short* __restrict__ Apre, int N) {
    int t = blockIdx.x * blockDim.x + threadIdx.x;
    int v = t >> 4;
    if (v >= N) return;
    const int c = (t & 15) * 8;
    const int r0 = rowptr[v], r1 = rowptr[v + 1];
    float acc[8] = {0.f,0.f,0.f,0.f,0.f,0.f,0.f,0.f};
    for (int j = r0; j < r1; j++) {
        const int d = csr[j];
        short8 nv = *(const short8*)(node + (size_t)d * 128 + c);
#pragma unroll
        for (int k = 0; k < 8; k++) acc[k] += bf2f((unsigned short)nv[k]);
    }
    const float dg = (float)(r1 - r0);
    short8 me = *(const short8*)(node + (size_t)v * 128 + c);
    short8 o;
#pragma unroll
    for (int k = 0; k < 8; k++) o[k] = (short)f2bf(dg * bf2f((unsigned short)me[k]));
    *(short8*)(A2 + (size_t)v * 256 + c) = o;
#pragma unroll
    for (int k = 0; k < 8; k++) o[k] = (short)f2bf(acc[k]);
    *(short8*)(A2 + (size_t)v * 256 + 128 + c) = o;
#pragma unroll
    for (int k = 0; k < 8; k++) o[k] = (short)f2bf(gelu_exact(bf2f((unsigned short)me[k])));
    *(short8*)(Apre + (size_t)v * 384 + c) = o;
#pragma unroll
    for (int k = 0; k < 8; k++) o[k] = (short)f2bf(gelu_exact(acc[k]));
    *(short8*)(Apre + (size_t)v * 384 + 128 + c) = o;
}

extern "C" void kernel_launch(void* const* d_in, const int* in_sizes, int n_in,
                              void* d_out, int out_size, void* d_ws, size_t ws_size,
                              hipStream_t stream) {
    const float* x  = (const float*)d_in[0];
    const int*   ei = (const int*)d_in[1];
    const float* Wn = (const float*)d_in[2];
    const float* bn = (const float*)d_in[3];
    const float* We = (const float*)d_in[4];
    const float* be = (const float*)d_in[5];
    const float* Wu = (const float*)d_in[6];
    const float* bu = (const float*)d_in[7];

    const int N = in_sizes[0] / 128;
    const int E = in_sizes[1] / 2;
    const int nWn = in_sizes[2], nWe = in_sizes[4], nWu = in_sizes[6];
    const int nsb = (N + SCAN_ELEMS - 1) / SCAN_ELEMS;

    char* ws = (char*)d_ws;
    size_t off = 0;
    unsigned short* node = (unsigned short*)(ws + off); off += (size_t)N * 128 * 2;
    int* deg = (int*)(ws + off);                        off += (size_t)N * 4;
    int* flag = (int*)(ws + off);                       off += 256;
    off = (off + 255) & ~(size_t)255;
    int* rowptr = (int*)(ws + off);                     off += (size_t)(N + 1) * 4;
    off = (off + 255) & ~(size_t)255;
    int* cursor = (int*)(ws + off);                     off += (size_t)N * 4;
    off = (off + 255) & ~(size_t)255;
    int* blocksum = (int*)(ws + off);                   off += (size_t)(nsb + 1) * 4;
    off = (off + 255) & ~(size_t)255;
    int* csr = (int*)(ws + off);                        off += (size_t)E * 4;
    off = (off + 255) & ~(size_t)255;
    unsigned short* A2 = (unsigned short*)(ws + off);   off += (size_t)N * 256 * 2;
    off = (off + 255) & ~(size_t)255;
    unsigned short* Apre = (unsigned short*)(ws + off); off += (size_t)N * 384 * 2;
    off = (off + 255) & ~(size_t)255;
    unsigned short* Wnb = (unsigned short*)(ws + off);  off += (size_t)nWn * 2;
    unsigned short* Web = (unsigned short*)(ws + off);  off += (size_t)nWe * 2;
    unsigned short* Wub = (unsigned short*)(ws + off);  off += (size_t)nWu * 2;

    // zero deg only (rowptr/cursor fully written by scan_apply)
    hipMemsetAsync(deg, 0, (size_t)N * 4, stream);

    const int mblocks = (N + 63) / 64;

    // 0a. weights fp32 -> bf16
    int maxn = nWu > nWe ? nWu : nWe; if (nWn > maxn) maxn = nWn;
    cvt3_kernel<<<(maxn / 4 + 255) / 256, 256, 0, stream>>>(Wn, nWn, We, nWe, Wu, nWu, Wnb, Web, Wub);
    // 0b. edge_index layout detect
    detect_kernel<<<1, 64, 0, stream>>>(ei, E, flag);
    // 1. node = x @ Wn^T + bn   (x fp32 -> bf16 inline)
    gemm_bt<128, 0, true, false><<<mblocks, 256, 0, stream>>>(x, Wnb, bn, node, 128, 0, nullptr, N);
    // 2. CSR build: histogram -> 3-phase scan -> fill
    deg_kernel<<<(E + 255) / 256, 256, 0, stream>>>(ei, flag, deg, E, N);
    scan_partial<<<nsb, 256, 0, stream>>>(deg, blocksum, N);
    scan_offsets<<<1, 64, 0, stream>>>(blocksum, nsb, rowptr, N);
    scan_apply<<<nsb, 256, 0, stream>>>(deg, blocksum, rowptr, cursor, N);
    fill_kernel<<<(E + 255) / 256, 256, 0, stream>>>(ei, flag, cursor, csr, E, N);
    // 3. gather nbr_sum + build A2 / Apre[:,0:256]  (no atomics)
    gather_build_kernel<<<((size_t)N * 16 + 255) / 256, 256, 0, stream>>>(rowptr, csr, node, A2, Apre, N);
    // 4. edge_sum = A2 @ We^T + deg*be, gelu -> Apre[:,256:384]
    gemm_bt<256, 1, false, false><<<mblocks, 256, 0, stream>>>(A2, Web, be, Apre, 384, 256, deg, N);
    // 5. out = Apre @ Wu^T + bu  (fp32 out)
    gemm_bt<384, 0, false, true><<<mblocks, 256, 0, stream>>>(Apre, Wub, bu, d_out, 128, 0, nullptr, N);
}

// Round 5
// 329.536 us; speedup vs baseline: 9.2496x; 1.0859x over previous
//
#include <hip/hip_runtime.h>
#include <hip/hip_bf16.h>
#include <math.h>

typedef __attribute__((ext_vector_type(8))) short short8;
typedef __attribute__((ext_vector_type(4))) float f32x4;

__device__ __forceinline__ float bf2f(unsigned short u) {
    union { unsigned int i; float f; } c; c.i = ((unsigned int)u) << 16; return c.f;
}
__device__ __forceinline__ unsigned short f2bf(float f) {
    __hip_bfloat16 h = __float2bfloat16(f);   // RNE
    union { __hip_bfloat16 h; unsigned short u; } c; c.h = h; return c.u;
}
__device__ __forceinline__ float gelu_exact(float x) {
    return 0.5f * x * (1.0f + erff(x * 0.7071067811865475f));
}
__device__ __forceinline__ short8 gelu_frag(short8 a) {
    short8 o;
#pragma unroll
    for (int k = 0; k < 8; k++) o[k] = (short)f2bf(gelu_exact(bf2f((unsigned short)a[k])));
    return o;
}

// Per-block edge-layout detect: int64 (high words zero) vs int32.
__device__ __forceinline__ int detect_flag(const int* ei, int E) {
    int orv = 0;
    int lim = (E < 64) ? E : 64;
    for (int i = 0; i < lim; i++) orv |= ei[2 * i + 1];
    return (orv == 0) ? 1 : 0;
}
__device__ __forceinline__ int ld_src(const int* ei, int flag, int E, int e) {
    return flag ? ei[2 * (size_t)e] : ei[e];
}
__device__ __forceinline__ int ld_dst(const int* ei, int flag, int E, int e) {
    return flag ? ei[2 * (size_t)(E + e)] : ei[E + e];
}

// ---------------- Kernel A: cvt3 (weights fp32->bf16)  ||  deg histogram ----------------
__launch_bounds__(256)
__global__ void pre_kernel(const float* __restrict__ s0, int n0,
                           const float* __restrict__ s1, int n1,
                           const float* __restrict__ s2, int n2,
                           unsigned short* __restrict__ d0,
                           unsigned short* __restrict__ d1,
                           unsigned short* __restrict__ d2,
                           int ncvt,
                           const int* __restrict__ ei, int* __restrict__ deg,
                           int E, int Nn) {
    if ((int)blockIdx.x < ncvt) {
        int t4 = (blockIdx.x * 256 + threadIdx.x) * 4;
        if (t4 < n0) {
            float4 f = *(const float4*)(s0 + t4);
            ushort4 o = { f2bf(f.x), f2bf(f.y), f2bf(f.z), f2bf(f.w) };
            *(ushort4*)(d0 + t4) = o;
        }
        if (t4 < n1) {
            float4 f = *(const float4*)(s1 + t4);
            ushort4 o = { f2bf(f.x), f2bf(f.y), f2bf(f.z), f2bf(f.w) };
            *(ushort4*)(d1 + t4) = o;
        }
        if (t4 < n2) {
            float4 f = *(const float4*)(s2 + t4);
            ushort4 o = { f2bf(f.x), f2bf(f.y), f2bf(f.z), f2bf(f.w) };
            *(ushort4*)(d2 + t4) = o;
        }
        return;
    }
    __shared__ int sflag;
    if (threadIdx.x == 0) sflag = detect_flag(ei, E);
    __syncthreads();
    int e = (blockIdx.x - ncvt) * 256 + threadIdx.x;
    if (e >= E) return;
    int s = ld_src(ei, sflag, E, e);
    if ((unsigned)s >= (unsigned)Nn) return;
    atomicAdd(&deg[s], 1);
}

// ---------------- Three-phase scan ----------------
#define SCAN_ELEMS 2048
__launch_bounds__(256)
__global__ void scan_partial(const int* __restrict__ deg, int* __restrict__ blocksum, int N) {
    __shared__ int red[256];
    const int t = threadIdx.x;
    const int base = blockIdx.x * SCAN_ELEMS + t * 8;
    int s = 0;
#pragma unroll
    for (int i = 0; i < 8; i++) { int idx = base + i; if (idx < N) s += deg[idx]; }
    red[t] = s;
    __syncthreads();
    for (int d = 128; d > 0; d >>= 1) {
        if (t < d) red[t] += red[t + d];
        __syncthreads();
    }
    if (t == 0) blocksum[blockIdx.x] = red[0];
}

__global__ void scan_offsets(int* __restrict__ blocksum, int nb,
                             int* __restrict__ rowptr, int N) {
    if (threadIdx.x == 0 && blockIdx.x == 0) {
        int run = 0;
        for (int i = 0; i < nb; i++) { int v = blocksum[i]; blocksum[i] = run; run += v; }
        rowptr[N] = run;
    }
}

__launch_bounds__(256)
__global__ void scan_apply(const int* __restrict__ deg, const int* __restrict__ blocksum,
                           int* __restrict__ rowptr, int* __restrict__ cursor, int N) {
    __shared__ int part[256];
    const int t = threadIdx.x;
    const int base = blockIdx.x * SCAN_ELEMS + t * 8;
    int d8[8];
    int s = 0;
#pragma unroll
    for (int i = 0; i < 8; i++) {
        int idx = base + i;
        d8[i] = (idx < N) ? deg[idx] : 0;
        s += d8[i];
    }
    const int mysum = s;
    part[t] = s;
    __syncthreads();
    for (int d = 1; d < 256; d <<= 1) {
        int v = (t >= d) ? part[t - d] : 0;
        __syncthreads();
        part[t] += v;
        __syncthreads();
    }
    int run = blocksum[blockIdx.x] + part[t] - mysum;
#pragma unroll
    for (int i = 0; i < 8; i++) {
        int idx = base + i;
        if (idx < N) { rowptr[idx] = run; cursor[idx] = run; run += d8[i]; }
    }
}

// ---------------- Kernel E: GEMM1 (node = x@Wn^T + bn, bf16 out) || CSR fill ----------------
__device__ __forceinline__ void gemm1_body(int bid,
                                           const float* __restrict__ x,
                                           const unsigned short* __restrict__ W,
                                           const float* __restrict__ bias,
                                           unsigned short* __restrict__ out,
                                           int Nrows) {
    const int wave = threadIdx.x >> 6;
    const int lane = threadIdx.x & 63;
    const int m    = lane & 15;
    const int kq   = lane >> 4;
    const int row  = bid * 64 + wave * 16 + m;
    const bool rowok = row < Nrows;

    f32x4 acc[8];
#pragma unroll
    for (int i = 0; i < 8; i++) acc[i] = (f32x4){0.f, 0.f, 0.f, 0.f};

    for (int kb = 0; kb < 4; kb++) {
        const int k0 = kb * 32 + kq * 8;
        short8 a = (short8){0,0,0,0,0,0,0,0};
        if (rowok) {
            const float* arow = x + (size_t)row * 128;
            float4 f0 = *(const float4*)(arow + k0);
            float4 f1 = *(const float4*)(arow + k0 + 4);
            a[0] = (short)f2bf(f0.x); a[1] = (short)f2bf(f0.y);
            a[2] = (short)f2bf(f0.z); a[3] = (short)f2bf(f0.w);
            a[4] = (short)f2bf(f1.x); a[5] = (short)f2bf(f1.y);
            a[6] = (short)f2bf(f1.z); a[7] = (short)f2bf(f1.w);
        }
#pragma unroll
        for (int nt = 0; nt < 8; nt++) {
            const int j = nt * 16 + m;
            short8 b = *(const short8*)(W + (size_t)j * 128 + k0);
            acc[nt] = __builtin_amdgcn_mfma_f32_16x16x32_bf16(a, b, acc[nt], 0, 0, 0);
        }
    }
    const int ocol = lane & 15;
    const int orow_base = bid * 64 + wave * 16 + (lane >> 4) * 4;
#pragma unroll
    for (int nt = 0; nt < 8; nt++) {
        const int col = nt * 16 + ocol;
        const float bval = bias[col];
#pragma unroll
        for (int r = 0; r < 4; r++) {
            const int orow = orow_base + r;
            if (orow < Nrows)
                out[(size_t)orow * 128 + col] = f2bf(acc[nt][r] + bval);
        }
    }
}

__launch_bounds__(256)
__global__ void gemm1_fill(const float* __restrict__ x,
                           const unsigned short* __restrict__ Wnb,
                           const float* __restrict__ bn,
                           unsigned short* __restrict__ node,
                           const int* __restrict__ ei,
                           int* __restrict__ cursor, int* __restrict__ csr,
                           int E, int N, int gemmBlocks) {
    if ((int)blockIdx.x < gemmBlocks) {
        gemm1_body(blockIdx.x, x, Wnb, bn, node, N);
        return;
    }
    __shared__ int sflag;
    if (threadIdx.x == 0) sflag = detect_flag(ei, E);
    __syncthreads();
    int e = (blockIdx.x - gemmBlocks) * 256 + threadIdx.x;
    if (e >= E) return;
    int s = ld_src(ei, sflag, E, e);
    int d = ld_dst(ei, sflag, E, e);
    if ((unsigned)s >= (unsigned)N || (unsigned)d >= (unsigned)N) return;
    int p = atomicAdd(&cursor[s], 1);
    csr[p] = d;
}

// ---------------- Mega kernel: gather + GEMM2 + GEMM3 per 64-row tile ----------------
// LDS tiles stride 136 bf16 (68 dw == 4 mod 32 -> optimal b128 bank spread).
#define TS 136
__launch_bounds__(256)
__global__ void mega_kernel(const int* __restrict__ rowptr, const int* __restrict__ csr,
                            const unsigned short* __restrict__ node,
                            const unsigned short* __restrict__ Web,   // [128][256]
                            const float* __restrict__ be,
                            const unsigned short* __restrict__ Wub,   // [128][384]
                            const float* __restrict__ bu,
                            float* __restrict__ out, int N) {
    __shared__ unsigned short nodeT[64 * TS];
    __shared__ unsigned short nbrT[64 * TS];
    __shared__ unsigned short PT[64 * TS];
    __shared__ int degT[64];

    const int v0 = blockIdx.x * 64;

    // ---- phase g: own rows + neighbor gather (4 threads/node, 32 ch each) ----
    {
        const int ln = threadIdx.x >> 2;
        const int cq = (threadIdx.x & 3) * 32;
        const int v  = v0 + ln;
        int r0 = 0, r1 = 0;
        if (v < N) { r0 = rowptr[v]; r1 = rowptr[v + 1]; }
        if ((threadIdx.x & 3) == 0) degT[ln] = r1 - r0;
#pragma unroll
        for (int q = 0; q < 4; q++) {
            short8 own = (short8){0,0,0,0,0,0,0,0};
            if (v < N) own = *(const short8*)(node + (size_t)v * 128 + cq + q * 8);
            *(short8*)(nodeT + ln * TS + cq + q * 8) = own;
        }
        float acc[32];
#pragma unroll
        for (int i = 0; i < 32; i++) acc[i] = 0.f;
        for (int j = r0; j < r1; j++) {
            const int d = csr[j];
#pragma unroll
            for (int q = 0; q < 4; q++) {
                short8 nv = *(const short8*)(node + (size_t)d * 128 + cq + q * 8);
#pragma unroll
                for (int k = 0; k < 8; k++) acc[q * 8 + k] += bf2f((unsigned short)nv[k]);
            }
        }
#pragma unroll
        for (int q = 0; q < 4; q++) {
            short8 o;
#pragma unroll
            for (int k = 0; k < 8; k++) o[k] = (short)f2bf(acc[q * 8 + k]);
            *(short8*)(nbrT + ln * TS + cq + q * 8) = o;
        }
    }
    __syncthreads();

    const int wave = threadIdx.x >> 6;
    const int lane = threadIdx.x & 63;
    const int m    = lane & 15;
    const int kq   = lane >> 4;
    const int lrow = wave * 16 + m;
    const int ocol = lane & 15;
    const int orow_base = wave * 16 + (lane >> 4) * 4;   // local row in tile

    // ---- phase 2: P = gelu(deg*(node@We1^T + be) + nbr@We2^T) ----
    {
        f32x4 at[8], an[8];
#pragma unroll
        for (int i = 0; i < 8; i++) { at[i] = (f32x4){0.f,0.f,0.f,0.f}; an[i] = (f32x4){0.f,0.f,0.f,0.f}; }
        for (int kb = 0; kb < 4; kb++) {
            const int k0 = kb * 32 + kq * 8;
            short8 afn = *(const short8*)(nodeT + lrow * TS + k0);
            short8 afb = *(const short8*)(nbrT + lrow * TS + k0);
#pragma unroll
            for (int nt = 0; nt < 8; nt++) {
                const int j = nt * 16 + m;
                short8 b1 = *(const short8*)(Web + (size_t)j * 256 + k0);
                short8 b2 = *(const short8*)(Web + (size_t)j * 256 + 128 + k0);
                at[nt] = __builtin_amdgcn_mfma_f32_16x16x32_bf16(afn, b1, at[nt], 0, 0, 0);
                an[nt] = __builtin_amdgcn_mfma_f32_16x16x32_bf16(afb, b2, an[nt], 0, 0, 0);
            }
        }
#pragma unroll
        for (int nt = 0; nt < 8; nt++) {
            const int col = nt * 16 + ocol;
            const float bval = be[col];
#pragma unroll
            for (int r = 0; r < 4; r++) {
                const int orow = orow_base + r;
                const float dg = (float)degT[orow];
                const float p  = gelu_exact(dg * (at[nt][r] + bval) + an[nt][r]);
                PT[orow * TS + col] = f2bf(p);
            }
        }
    }
    __syncthreads();

    // ---- phase 3: out = [gelu(node) | gelu(nbr) | P] @ Wu^T + bu  (fp32 out) ----
    {
        f32x4 a3[8];
#pragma unroll
        for (int i = 0; i < 8; i++) a3[i] = (f32x4){0.f,0.f,0.f,0.f};
        for (int kb = 0; kb < 4; kb++) {
            const int k0 = kb * 32 + kq * 8;
            short8 afn = gelu_frag(*(const short8*)(nodeT + lrow * TS + k0));
            short8 afb = gelu_frag(*(const short8*)(nbrT + lrow * TS + k0));
            short8 afp = *(const short8*)(PT + lrow * TS + k0);
#pragma unroll
            for (int nt = 0; nt < 8; nt++) {
                const int j = nt * 16 + m;
                short8 b1 = *(const short8*)(Wub + (size_t)j * 384 + k0);
                short8 b2 = *(const short8*)(Wub + (size_t)j * 384 + 128 + k0);
                short8 b3 = *(const short8*)(Wub + (size_t)j * 384 + 256 + k0);
                a3[nt] = __builtin_amdgcn_mfma_f32_16x16x32_bf16(afn, b1, a3[nt], 0, 0, 0);
                a3[nt] = __builtin_amdgcn_mfma_f32_16x16x32_bf16(afb, b2, a3[nt], 0, 0, 0);
                a3[nt] = __builtin_amdgcn_mfma_f32_16x16x32_bf16(afp, b3, a3[nt], 0, 0, 0);
            }
        }
#pragma unroll
        for (int nt = 0; nt < 8; nt++) {
            const int col = nt * 16 + ocol;
            const float bval = bu[col];
#pragma unroll
            for (int r = 0; r < 4; r++) {
                const int orow = v0 + orow_base + r;
                if (orow < N)
                    out[(size_t)orow * 128 + col] = a3[nt][r] + bval;
            }
        }
    }
}

extern "C" void kernel_launch(void* const* d_in, const int* in_sizes, int n_in,
                              void* d_out, int out_size, void* d_ws, size_t ws_size,
                              hipStream_t stream) {
    const float* x  = (const float*)d_in[0];
    const int*   ei = (const int*)d_in[1];
    const float* Wn = (const float*)d_in[2];
    const float* bn = (const float*)d_in[3];
    const float* We = (const float*)d_in[4];
    const float* be = (const float*)d_in[5];
    const float* Wu = (const float*)d_in[6];
    const float* bu = (const float*)d_in[7];

    const int N = in_sizes[0] / 128;
    const int E = in_sizes[1] / 2;
    const int nWn = in_sizes[2], nWe = in_sizes[4], nWu = in_sizes[6];
    const int nsb = (N + SCAN_ELEMS - 1) / SCAN_ELEMS;

    char* ws = (char*)d_ws;
    size_t off = 0;
    unsigned short* node = (unsigned short*)(ws + off); off += (size_t)N * 128 * 2;
    int* deg = (int*)(ws + off);                        off += (size_t)N * 4;
    off = (off + 255) & ~(size_t)255;
    int* rowptr = (int*)(ws + off);                     off += (size_t)(N + 1) * 4;
    off = (off + 255) & ~(size_t)255;
    int* cursor = (int*)(ws + off);                     off += (size_t)N * 4;
    off = (off + 255) & ~(size_t)255;
    int* blocksum = (int*)(ws + off);                   off += (size_t)(nsb + 1) * 4;
    off = (off + 255) & ~(size_t)255;
    int* csr = (int*)(ws + off);                        off += (size_t)E * 4;
    off = (off + 255) & ~(size_t)255;
    unsigned short* Wnb = (unsigned short*)(ws + off);  off += (size_t)nWn * 2;
    unsigned short* Web = (unsigned short*)(ws + off);  off += (size_t)nWe * 2;
    unsigned short* Wub = (unsigned short*)(ws + off);  off += (size_t)nWu * 2;

    hipMemsetAsync(deg, 0, (size_t)N * 4, stream);

    const int mblocks = (N + 63) / 64;
    const int eblocks = (E + 255) / 256;

    // A. cvt3 || deg
    int maxn = nWu > nWe ? nWu : nWe; if (nWn > maxn) maxn = nWn;
    const int ncvt = (maxn / 4 + 255) / 256;
    pre_kernel<<<ncvt + eblocks, 256, 0, stream>>>(Wn, nWn, We, nWe, Wu, nWu,
                                                   Wnb, Web, Wub, ncvt, ei, deg, E, N);
    // B-D. scan deg -> rowptr/cursor
    scan_partial<<<nsb, 256, 0, stream>>>(deg, blocksum, N);
    scan_offsets<<<1, 64, 0, stream>>>(blocksum, nsb, rowptr, N);
    scan_apply<<<nsb, 256, 0, stream>>>(deg, blocksum, rowptr, cursor, N);
    // E. GEMM1 || CSR fill
    gemm1_fill<<<mblocks + eblocks, 256, 0, stream>>>(x, Wnb, bn, node, ei, cursor, csr, E, N, mblocks);
    // F. gather + GEMM2 + GEMM3
    mega_kernel<<<mblocks, 256, 0, stream>>>(rowptr, csr, node, Web, be, Wub, bu, (float*)d_out, N);
}

// Round 6
// 318.814 us; speedup vs baseline: 9.5606x; 1.0336x over previous
//
#include <hip/hip_runtime.h>
#include <hip/hip_bf16.h>
#include <math.h>

typedef __attribute__((ext_vector_type(8))) short short8;
typedef __attribute__((ext_vector_type(4))) float f32x4;

__device__ __forceinline__ float bf2f(unsigned short u) {
    union { unsigned int i; float f; } c; c.i = ((unsigned int)u) << 16; return c.f;
}
__device__ __forceinline__ unsigned short f2bf(float f) {
    __hip_bfloat16 h = __float2bfloat16(f);   // RNE
    union { __hip_bfloat16 h; unsigned short u; } c; c.h = h; return c.u;
}
__device__ __forceinline__ float gelu_exact(float x) {
    return 0.5f * x * (1.0f + erff(x * 0.7071067811865475f));
}
__device__ __forceinline__ short8 gelu_frag(short8 a) {
    short8 o;
#pragma unroll
    for (int k = 0; k < 8; k++) o[k] = (short)f2bf(gelu_exact(bf2f((unsigned short)a[k])));
    return o;
}

// Per-block edge-layout detect: int64 (high words zero) vs int32.
__device__ __forceinline__ int detect_flag(const int* ei, int E) {
    int orv = 0;
    int lim = (E < 64) ? E : 64;
    for (int i = 0; i < lim; i++) orv |= ei[2 * i + 1];
    return (orv == 0) ? 1 : 0;
}
__device__ __forceinline__ int ld_src(const int* ei, int flag, int E, int e) {
    return flag ? ei[2 * (size_t)e] : ei[e];
}
__device__ __forceinline__ int ld_dst(const int* ei, int flag, int E, int e) {
    return flag ? ei[2 * (size_t)(E + e)] : ei[E + e];
}

// ---------------- Kernel A: cvt3 (weights fp32->bf16)  ||  deg histogram ----------------
__launch_bounds__(256)
__global__ void pre_kernel(const float* __restrict__ s0, int n0,
                           const float* __restrict__ s1, int n1,
                           const float* __restrict__ s2, int n2,
                           unsigned short* __restrict__ d0,
                           unsigned short* __restrict__ d1,
                           unsigned short* __restrict__ d2,
                           int ncvt,
                           const int* __restrict__ ei, int* __restrict__ deg,
                           int E, int Nn) {
    if ((int)blockIdx.x < ncvt) {
        int t4 = (blockIdx.x * 256 + threadIdx.x) * 4;
        if (t4 < n0) {
            float4 f = *(const float4*)(s0 + t4);
            ushort4 o = { f2bf(f.x), f2bf(f.y), f2bf(f.z), f2bf(f.w) };
            *(ushort4*)(d0 + t4) = o;
        }
        if (t4 < n1) {
            float4 f = *(const float4*)(s1 + t4);
            ushort4 o = { f2bf(f.x), f2bf(f.y), f2bf(f.z), f2bf(f.w) };
            *(ushort4*)(d1 + t4) = o;
        }
        if (t4 < n2) {
            float4 f = *(const float4*)(s2 + t4);
            ushort4 o = { f2bf(f.x), f2bf(f.y), f2bf(f.z), f2bf(f.w) };
            *(ushort4*)(d2 + t4) = o;
        }
        return;
    }
    __shared__ int sflag;
    if (threadIdx.x == 0) sflag = detect_flag(ei, E);
    __syncthreads();
    int e = (blockIdx.x - ncvt) * 256 + threadIdx.x;
    if (e >= E) return;
    int s = ld_src(ei, sflag, E, e);
    if ((unsigned)s >= (unsigned)Nn) return;
    atomicAdd(&deg[s], 1);
}

// ---------------- Three-phase scan ----------------
#define SCAN_ELEMS 2048
__launch_bounds__(256)
__global__ void scan_partial(const int* __restrict__ deg, int* __restrict__ blocksum, int N) {
    __shared__ int red[256];
    const int t = threadIdx.x;
    const int base = blockIdx.x * SCAN_ELEMS + t * 8;
    int s = 0;
#pragma unroll
    for (int i = 0; i < 8; i++) { int idx = base + i; if (idx < N) s += deg[idx]; }
    red[t] = s;
    __syncthreads();
    for (int d = 128; d > 0; d >>= 1) {
        if (t < d) red[t] += red[t + d];
        __syncthreads();
    }
    if (t == 0) blocksum[blockIdx.x] = red[0];
}

__global__ void scan_offsets(int* __restrict__ blocksum, int nb,
                             int* __restrict__ rowptr, int N) {
    if (threadIdx.x == 0 && blockIdx.x == 0) {
        int run = 0;
        for (int i = 0; i < nb; i++) { int v = blocksum[i]; blocksum[i] = run; run += v; }
        rowptr[N] = run;
    }
}

__launch_bounds__(256)
__global__ void scan_apply(const int* __restrict__ deg, const int* __restrict__ blocksum,
                           int* __restrict__ rowptr, int* __restrict__ cursor, int N) {
    __shared__ int part[256];
    const int t = threadIdx.x;
    const int base = blockIdx.x * SCAN_ELEMS + t * 8;
    int d8[8];
    int s = 0;
#pragma unroll
    for (int i = 0; i < 8; i++) {
        int idx = base + i;
        d8[i] = (idx < N) ? deg[idx] : 0;
        s += d8[i];
    }
    const int mysum = s;
    part[t] = s;
    __syncthreads();
    for (int d = 1; d < 256; d <<= 1) {
        int v = (t >= d) ? part[t - d] : 0;
        __syncthreads();
        part[t] += v;
        __syncthreads();
    }
    int run = blocksum[blockIdx.x] + part[t] - mysum;
#pragma unroll
    for (int i = 0; i < 8; i++) {
        int idx = base + i;
        if (idx < N) { rowptr[idx] = run; cursor[idx] = run; run += d8[i]; }
    }
}

// ---------------- Kernel E: GEMM1 (node = x@Wn^T + bn, bf16 out) || CSR fill ----------------
__device__ __forceinline__ void gemm1_body(int bid,
                                           const float* __restrict__ x,
                                           const unsigned short* __restrict__ W,
                                           const float* __restrict__ bias,
                                           unsigned short* __restrict__ out,
                                           int Nrows) {
    const int wave = threadIdx.x >> 6;
    const int lane = threadIdx.x & 63;
    const int m    = lane & 15;
    const int kq   = lane >> 4;
    const int row  = bid * 64 + wave * 16 + m;
    const bool rowok = row < Nrows;

    f32x4 acc[8];
#pragma unroll
    for (int i = 0; i < 8; i++) acc[i] = (f32x4){0.f, 0.f, 0.f, 0.f};

    for (int kb = 0; kb < 4; kb++) {
        const int k0 = kb * 32 + kq * 8;
        short8 a = (short8){0,0,0,0,0,0,0,0};
        if (rowok) {
            const float* arow = x + (size_t)row * 128;
            float4 f0 = *(const float4*)(arow + k0);
            float4 f1 = *(const float4*)(arow + k0 + 4);
            a[0] = (short)f2bf(f0.x); a[1] = (short)f2bf(f0.y);
            a[2] = (short)f2bf(f0.z); a[3] = (short)f2bf(f0.w);
            a[4] = (short)f2bf(f1.x); a[5] = (short)f2bf(f1.y);
            a[6] = (short)f2bf(f1.z); a[7] = (short)f2bf(f1.w);
        }
#pragma unroll
        for (int nt = 0; nt < 8; nt++) {
            const int j = nt * 16 + m;
            short8 b = *(const short8*)(W + (size_t)j * 128 + k0);
            acc[nt] = __builtin_amdgcn_mfma_f32_16x16x32_bf16(a, b, acc[nt], 0, 0, 0);
        }
    }
    const int ocol = lane & 15;
    const int orow_base = bid * 64 + wave * 16 + (lane >> 4) * 4;
#pragma unroll
    for (int nt = 0; nt < 8; nt++) {
        const int col = nt * 16 + ocol;
        const float bval = bias[col];
#pragma unroll
        for (int r = 0; r < 4; r++) {
            const int orow = orow_base + r;
            if (orow < Nrows)
                out[(size_t)orow * 128 + col] = f2bf(acc[nt][r] + bval);
        }
    }
}

__launch_bounds__(256)
__global__ void gemm1_fill(const float* __restrict__ x,
                           const unsigned short* __restrict__ Wnb,
                           const float* __restrict__ bn,
                           unsigned short* __restrict__ node,
                           const int* __restrict__ ei,
                           int* __restrict__ cursor, int* __restrict__ csr,
                           int E, int N, int gemmBlocks) {
    if ((int)blockIdx.x < gemmBlocks) {
        gemm1_body(blockIdx.x, x, Wnb, bn, node, N);
        return;
    }
    __shared__ int sflag;
    if (threadIdx.x == 0) sflag = detect_flag(ei, E);
    __syncthreads();
    int e = (blockIdx.x - gemmBlocks) * 256 + threadIdx.x;
    if (e >= E) return;
    int s = ld_src(ei, sflag, E, e);
    int d = ld_dst(ei, sflag, E, e);
    if ((unsigned)s >= (unsigned)N || (unsigned)d >= (unsigned)N) return;
    int p = atomicAdd(&cursor[s], 1);
    csr[p] = d;
}

// ---------------- Gather: nbr[v] = sum node[csr[j]]  (16 thr/node, unroll x4) ----------------
__launch_bounds__(256)
__global__ void gather_kernel(const int* __restrict__ rowptr, const int* __restrict__ csr,
                              const unsigned short* __restrict__ node,
                              unsigned short* __restrict__ nbr, int N) {
    int t = blockIdx.x * 256 + threadIdx.x;
    int v = t >> 4;
    if (v >= N) return;
    const int c = (t & 15) * 8;
    const int r0 = rowptr[v], r1 = rowptr[v + 1];
    float acc[8] = {0.f,0.f,0.f,0.f,0.f,0.f,0.f,0.f};
    int j = r0;
    for (; j + 4 <= r1; j += 4) {
        const int i0 = csr[j], i1 = csr[j + 1], i2 = csr[j + 2], i3 = csr[j + 3];
        short8 a0 = *(const short8*)(node + (size_t)i0 * 128 + c);
        short8 a1 = *(const short8*)(node + (size_t)i1 * 128 + c);
        short8 a2 = *(const short8*)(node + (size_t)i2 * 128 + c);
        short8 a3 = *(const short8*)(node + (size_t)i3 * 128 + c);
#pragma unroll
        for (int k = 0; k < 8; k++)
            acc[k] += (bf2f((unsigned short)a0[k]) + bf2f((unsigned short)a1[k]))
                    + (bf2f((unsigned short)a2[k]) + bf2f((unsigned short)a3[k]));
    }
    for (; j < r1; j++) {
        const int d = csr[j];
        short8 a0 = *(const short8*)(node + (size_t)d * 128 + c);
#pragma unroll
        for (int k = 0; k < 8; k++) acc[k] += bf2f((unsigned short)a0[k]);
    }
    short8 o;
#pragma unroll
    for (int k = 0; k < 8; k++) o[k] = (short)f2bf(acc[k]);
    *(short8*)(nbr + (size_t)v * 128 + c) = o;
}

// ---------------- GEMM2+3 fused per 64-row tile; LDS only for P (C->A transform) ----------------
#define TS 136
__launch_bounds__(256)
__global__ void gemm23_kernel(const int* __restrict__ rowptr,
                              const unsigned short* __restrict__ node,
                              const unsigned short* __restrict__ nbr,
                              const unsigned short* __restrict__ Web,   // [128][256]
                              const float* __restrict__ be,
                              const unsigned short* __restrict__ Wub,   // [128][384]
                              const float* __restrict__ bu,
                              float* __restrict__ out, int N) {
    __shared__ unsigned short PT[64 * TS];
    __shared__ int degT[64];

    const int v0 = blockIdx.x * 64;
    if (threadIdx.x < 64) {
        int v = v0 + threadIdx.x;
        degT[threadIdx.x] = (v < N) ? rowptr[v + 1] - rowptr[v] : 0;
    }

    const int wave = threadIdx.x >> 6;
    const int lane = threadIdx.x & 63;
    const int m    = lane & 15;
    const int kq   = lane >> 4;
    const int lrow = wave * 16 + m;
    const bool rowok = (v0 + lrow) < N;
    const unsigned short* nrow = node + (size_t)(v0 + lrow) * 128;
    const unsigned short* brow = nbr  + (size_t)(v0 + lrow) * 128;
    const int ocol = lane & 15;
    const int orow_base = wave * 16 + (lane >> 4) * 4;   // local row in tile
    const short8 zero = (short8){0,0,0,0,0,0,0,0};

    __syncthreads();   // degT ready

    // ---- phase 2: P = gelu(deg*(node@We1^T + be) + nbr@We2^T) ----
    {
        f32x4 at[8], an[8];
#pragma unroll
        for (int i = 0; i < 8; i++) { at[i] = (f32x4){0.f,0.f,0.f,0.f}; an[i] = (f32x4){0.f,0.f,0.f,0.f}; }
        for (int kb = 0; kb < 4; kb++) {
            const int k0 = kb * 32 + kq * 8;
            short8 afn = rowok ? *(const short8*)(nrow + k0) : zero;
            short8 afb = rowok ? *(const short8*)(brow + k0) : zero;
#pragma unroll
            for (int nt = 0; nt < 8; nt++) {
                const int j = nt * 16 + m;
                short8 b1 = *(const short8*)(Web + (size_t)j * 256 + k0);
                short8 b2 = *(const short8*)(Web + (size_t)j * 256 + 128 + k0);
                at[nt] = __builtin_amdgcn_mfma_f32_16x16x32_bf16(afn, b1, at[nt], 0, 0, 0);
                an[nt] = __builtin_amdgcn_mfma_f32_16x16x32_bf16(afb, b2, an[nt], 0, 0, 0);
            }
        }
#pragma unroll
        for (int nt = 0; nt < 8; nt++) {
            const int col = nt * 16 + ocol;
            const float bval = be[col];
#pragma unroll
            for (int r = 0; r < 4; r++) {
                const int orow = orow_base + r;
                const float dg = (float)degT[orow];
                PT[orow * TS + col] = f2bf(gelu_exact(dg * (at[nt][r] + bval) + an[nt][r]));
            }
        }
    }
    __syncthreads();

    // ---- phase 3: out = [gelu(node) | gelu(nbr) | P] @ Wu^T + bu  (fp32 out) ----
    {
        f32x4 a3[8];
#pragma unroll
        for (int i = 0; i < 8; i++) a3[i] = (f32x4){0.f,0.f,0.f,0.f};
        for (int kb = 0; kb < 4; kb++) {
            const int k0 = kb * 32 + kq * 8;
            short8 afn = rowok ? gelu_frag(*(const short8*)(nrow + k0)) : zero;
            short8 afb = rowok ? gelu_frag(*(const short8*)(brow + k0)) : zero;
            short8 afp = *(const short8*)(PT + lrow * TS + k0);
#pragma unroll
            for (int nt = 0; nt < 8; nt++) {
                const int j = nt * 16 + m;
                short8 b1 = *(const short8*)(Wub + (size_t)j * 384 + k0);
                short8 b2 = *(const short8*)(Wub + (size_t)j * 384 + 128 + k0);
                short8 b3 = *(const short8*)(Wub + (size_t)j * 384 + 256 + k0);
                a3[nt] = __builtin_amdgcn_mfma_f32_16x16x32_bf16(afn, b1, a3[nt], 0, 0, 0);
                a3[nt] = __builtin_amdgcn_mfma_f32_16x16x32_bf16(afb, b2, a3[nt], 0, 0, 0);
                a3[nt] = __builtin_amdgcn_mfma_f32_16x16x32_bf16(afp, b3, a3[nt], 0, 0, 0);
            }
        }
#pragma unroll
        for (int nt = 0; nt < 8; nt++) {
            const int col = nt * 16 + ocol;
            const float bval = bu[col];
#pragma unroll
            for (int r = 0; r < 4; r++) {
                const int orow = v0 + orow_base + r;
                if (orow < N)
                    out[(size_t)orow * 128 + col] = a3[nt][r] + bval;
            }
        }
    }
}

extern "C" void kernel_launch(void* const* d_in, const int* in_sizes, int n_in,
                              void* d_out, int out_size, void* d_ws, size_t ws_size,
                              hipStream_t stream) {
    const float* x  = (const float*)d_in[0];
    const int*   ei = (const int*)d_in[1];
    const float* Wn = (const float*)d_in[2];
    const float* bn = (const float*)d_in[3];
    const float* We = (const float*)d_in[4];
    const float* be = (const float*)d_in[5];
    const float* Wu = (const float*)d_in[6];
    const float* bu = (const float*)d_in[7];

    const int N = in_sizes[0] / 128;
    const int E = in_sizes[1] / 2;
    const int nWn = in_sizes[2], nWe = in_sizes[4], nWu = in_sizes[6];
    const int nsb = (N + SCAN_ELEMS - 1) / SCAN_ELEMS;

    char* ws = (char*)d_ws;
    size_t off = 0;
    unsigned short* node = (unsigned short*)(ws + off); off += (size_t)N * 128 * 2;
    unsigned short* nbr  = (unsigned short*)(ws + off); off += (size_t)N * 128 * 2;
    int* deg = (int*)(ws + off);                        off += (size_t)N * 4;
    off = (off + 255) & ~(size_t)255;
    int* rowptr = (int*)(ws + off);                     off += (size_t)(N + 1) * 4;
    off = (off + 255) & ~(size_t)255;
    int* cursor = (int*)(ws + off);                     off += (size_t)N * 4;
    off = (off + 255) & ~(size_t)255;
    int* blocksum = (int*)(ws + off);                   off += (size_t)(nsb + 1) * 4;
    off = (off + 255) & ~(size_t)255;
    int* csr = (int*)(ws + off);                        off += (size_t)E * 4;
    off = (off + 255) & ~(size_t)255;
    unsigned short* Wnb = (unsigned short*)(ws + off);  off += (size_t)nWn * 2;
    unsigned short* Web = (unsigned short*)(ws + off);  off += (size_t)nWe * 2;
    unsigned short* Wub = (unsigned short*)(ws + off);  off += (size_t)nWu * 2;

    hipMemsetAsync(deg, 0, (size_t)N * 4, stream);

    const int mblocks = (N + 63) / 64;
    const int eblocks = (E + 255) / 256;

    // A. cvt3 || deg
    int maxn = nWu > nWe ? nWu : nWe; if (nWn > maxn) maxn = nWn;
    const int ncvt = (maxn / 4 + 255) / 256;
    pre_kernel<<<ncvt + eblocks, 256, 0, stream>>>(Wn, nWn, We, nWe, Wu, nWu,
                                                   Wnb, Web, Wub, ncvt, ei, deg, E, N);
    // B-D. scan deg -> rowptr/cursor
    scan_partial<<<nsb, 256, 0, stream>>>(deg, blocksum, N);
    scan_offsets<<<1, 64, 0, stream>>>(blocksum, nsb, rowptr, N);
    scan_apply<<<nsb, 256, 0, stream>>>(deg, blocksum, rowptr, cursor, N);
    // E. GEMM1 || CSR fill
    gemm1_fill<<<mblocks + eblocks, 256, 0, stream>>>(x, Wnb, bn, node, ei, cursor, csr, E, N, mblocks);
    // F. gather (latency-optimized, full occupancy)
    gather_kernel<<<((size_t)N * 16 + 255) / 256, 256, 0, stream>>>(rowptr, csr, node, nbr, N);
    // G. GEMM2+3 fused
    gemm23_kernel<<<mblocks, 256, 0, stream>>>(rowptr, node, nbr, Web, be, Wub, bu, (float*)d_out, N);
}